// Round 3
// baseline (234.424 us; speedup 1.0000x reference)
//
#include <hip/hip_runtime.h>
#include <hip/hip_bf16.h>
#include <cstdint>
#include <cstddef>

#define N_  64
#define L_  196
#define T_  32
#define D_  512
#define ROWS1_ (N_ * L_)          // 12544
#define ROWS2_ (N_ * T_)          // 2048
#define MT1_   (ROWS1_ / 128)     // 98 m-tiles for problem 1
#define NWG1_  (MT1_ * 4)         // 392
#define NWG2_  ((ROWS2_ / 128) * 4) // 64

typedef __attribute__((ext_vector_type(8))) short short8;
typedef __attribute__((ext_vector_type(4))) float f32x4;

// f32 -> bf16 bits, round-to-nearest-even
__device__ inline unsigned short f2bf(float f) {
  unsigned u = __builtin_bit_cast(unsigned, f);
  u = u + 0x7FFFu + ((u >> 16) & 1u);
  return (unsigned short)(u >> 16);
}

// ---- fused: bf16 convert of f1/f2 rows + attention dot s = row @ w_att ------
// one wave per row; lane holds 8 f32 (two float4), writes two ushort4
__global__ __launch_bounds__(256)
void cvt_dots(const float* __restrict__ f1, const float* __restrict__ f2,
              const float* __restrict__ w,
              unsigned short* __restrict__ f1b, unsigned short* __restrict__ f2b,
              float* __restrict__ s1, float* __restrict__ s2) {
  int row = blockIdx.x * 4 + (threadIdx.x >> 6);
  int lane = threadIdx.x & 63;
  bool isf1 = row < ROWS1_;
  const float* src = isf1 ? (f1 + (size_t)row * D_) : (f2 + (size_t)(row - ROWS1_) * D_);
  unsigned short* dst = isf1 ? (f1b + (size_t)row * D_) : (f2b + (size_t)(row - ROWS1_) * D_);
  float4 x0 = ((const float4*)src)[lane];
  float4 x1 = ((const float4*)src)[lane + 64];
  float4 w0 = ((const float4*)w)[lane];
  float4 w1 = ((const float4*)w)[lane + 64];
  float d = x0.x * w0.x + x0.y * w0.y + x0.z * w0.z + x0.w * w0.w
          + x1.x * w1.x + x1.y * w1.y + x1.z * w1.z + x1.w * w1.w;
  ushort4 o0, o1;
  o0.x = f2bf(x0.x); o0.y = f2bf(x0.y); o0.z = f2bf(x0.z); o0.w = f2bf(x0.w);
  o1.x = f2bf(x1.x); o1.y = f2bf(x1.y); o1.z = f2bf(x1.z); o1.w = f2bf(x1.w);
  ((ushort4*)dst)[lane] = o0;
  ((ushort4*)dst)[lane + 64] = o1;
  #pragma unroll
  for (int s = 32; s; s >>= 1) d += __shfl_xor(d, s);
  if (lane == 0) {
    if (isf1) s1[row] = d; else s2[row - ROWS1_] = d;
  }
}

// ------------- weight transpose + convert: Wt[n][k] = bf16(W[k][n]) -----------
__global__ __launch_bounds__(256)
void wt_cvt(const float* __restrict__ w0, const float* __restrict__ w1,
            const float* __restrict__ w2, const float* __restrict__ w3,
            unsigned short* __restrict__ o0, unsigned short* __restrict__ o1,
            unsigned short* __restrict__ o2, unsigned short* __restrict__ o3) {
  const float* W = (blockIdx.y == 0) ? w0 : (blockIdx.y == 1) ? w1 : (blockIdx.y == 2) ? w2 : w3;
  unsigned short* O = (blockIdx.y == 0) ? o0 : (blockIdx.y == 1) ? o1 : (blockIdx.y == 2) ? o2 : o3;
  int k0 = (blockIdx.x >> 3) * 64, n0 = (blockIdx.x & 7) * 64;
  __shared__ float tl[64][65];
  int t = threadIdx.x;
  #pragma unroll
  for (int i = 0; i < 16; i++) {
    int e = t + i * 256;
    int r = e >> 6, c = e & 63;
    tl[r][c] = W[(size_t)(k0 + r) * D_ + n0 + c];
  }
  __syncthreads();
  #pragma unroll
  for (int i = 0; i < 16; i++) {
    int e = t + i * 256;
    int r = e >> 6, c = e & 63;
    O[(size_t)(n0 + r) * D_ + k0 + c] = f2bf(tl[c][r]);
  }
}

// ---------------- softmax over L for each (n,t) -> att (f32 output) ----------
__global__ __launch_bounds__(64)
void softmax_att(const float* __restrict__ s1, const float* __restrict__ s2,
                 const float* __restrict__ b_att, float* __restrict__ att) {
  int b = blockIdx.x;           // n*32 + t
  int n = b >> 5;
  int lane = threadIdx.x;
  float s2v = s2[b] + b_att[0];
  const float* s1n = s1 + (size_t)n * L_;
  float v[4];
  float mx = -1e30f;
  #pragma unroll
  for (int j = 0; j < 4; j++) {
    int l = lane + j * 64;
    v[j] = (l < L_) ? (s1n[l] + s2v) : -1e30f;
    mx = fmaxf(mx, v[j]);
  }
  #pragma unroll
  for (int s = 32; s; s >>= 1) mx = fmaxf(mx, __shfl_xor(mx, s));
  float sum = 0.f;
  #pragma unroll
  for (int j = 0; j < 4; j++) { v[j] = __expf(v[j] - mx); sum += v[j]; }
  #pragma unroll
  for (int s = 32; s; s >>= 1) sum += __shfl_xor(sum, s);
  float inv = 1.f / sum;
  float* an = att + (size_t)b * L_;
  #pragma unroll
  for (int j = 0; j < 4; j++) {
    int l = lane + j * 64;
    if (l < L_) an[l] = v[j] * inv;
  }
}

// -------- fused GLU GEMM (both problems in one grid) -------------------------
// out = tanh(X@W1+b1) * sigmoid(X@W2+b2); X bf16 [M][512], Wt bf16 [n][k]
// grid.x = NWG1_ + NWG2_ = 456 (%8==0), block 256 (4 waves, 2x2 of 128x128)
__global__ __launch_bounds__(256, 2)
void glu_gemm(const unsigned short* __restrict__ Xb1, const unsigned short* __restrict__ Xb2,
              const unsigned short* __restrict__ W1t_1, const unsigned short* __restrict__ W2t_1,
              const unsigned short* __restrict__ W1t_2, const unsigned short* __restrict__ W2t_2,
              const float* __restrict__ b1_1, const float* __restrict__ b2_1,
              const float* __restrict__ b1_2, const float* __restrict__ b2_2,
              float* __restrict__ o1, float* __restrict__ o0) {
  int nwg = gridDim.x;
  int q = nwg >> 3;                         // nwg % 8 == 0 by construction
  int orig = blockIdx.x;
  int bid = (orig & 7) * q + (orig >> 3);   // XCD-chunked swizzle (bijective)
  const unsigned short *Xb, *W1t, *W2t;
  const float *b1, *b2;
  float* out;
  if (bid < NWG1_) { Xb = Xb1; W1t = W1t_1; W2t = W2t_1; b1 = b1_1; b2 = b2_1; out = o1; }
  else { bid -= NWG1_; Xb = Xb2; W1t = W1t_2; W2t = W2t_2; b1 = b1_2; b2 = b2_2; out = o0; }
  int nt = bid & 3, mt = bid >> 2;
  int m0 = mt * 128, n0 = nt * 128;
  int t = threadIdx.x, lane = t & 63, wave = t >> 6;
  int wr = (wave >> 1) * 64, wc = (wave & 1) * 64;

  __shared__ alignas(16) unsigned short Xs[2][4096];      // [128][32]
  __shared__ alignas(16) unsigned short Ws[2][2][4096];   // [mat][128][32]

  auto stage = [&](int buf, int k0) {
    #pragma unroll
    for (int i = 0; i < 2; i++) {
      int c = t + i * 256;                      // 16B chunk id, row = c>>2, kc = c&3
      const unsigned short* g = Xb + (size_t)(m0 + (c >> 2)) * D_ + k0 + (c & 3) * 8;
      unsigned short* l = &Xs[buf][(size_t)(wave * 64 + i * 256) * 8];
      __builtin_amdgcn_global_load_lds((const __attribute__((address_space(1))) unsigned int*)g,
                                       (__attribute__((address_space(3))) unsigned int*)l,
                                       16, 0, 0);
    }
    #pragma unroll
    for (int w = 0; w < 2; w++) {
      const unsigned short* Wt = w ? W2t : W1t;
      #pragma unroll
      for (int i = 0; i < 2; i++) {
        int c = t + i * 256;
        const unsigned short* g = Wt + (size_t)(n0 + (c >> 2)) * D_ + k0 + (c & 3) * 8;
        unsigned short* l = &Ws[buf][w][(size_t)(wave * 64 + i * 256) * 8];
        __builtin_amdgcn_global_load_lds((const __attribute__((address_space(1))) unsigned int*)g,
                                         (__attribute__((address_space(3))) unsigned int*)l,
                                         16, 0, 0);
      }
    }
  };

  f32x4 acc1[4][4], acc2[4][4];
  #pragma unroll
  for (int i = 0; i < 4; i++)
    #pragma unroll
    for (int j = 0; j < 4; j++) { acc1[i][j] = (f32x4)(0.f); acc2[i][j] = (f32x4)(0.f); }

  stage(0, 0);
  int cur = 0;
  int arow = lane & 15, ak = (lane >> 4) * 8;
  for (int ks = 0; ks < 16; ++ks) {
    __syncthreads();                          // drains vmcnt before barrier
    if (ks < 15) stage(cur ^ 1, (ks + 1) * 32);
    short8 a[4], bf1[4], bf2[4];
    #pragma unroll
    for (int mf = 0; mf < 4; mf++)
      a[mf] = *(const short8*)&Xs[cur][(wr + mf * 16 + arow) * 32 + ak];
    #pragma unroll
    for (int nf = 0; nf < 4; nf++) {
      bf1[nf] = *(const short8*)&Ws[cur][0][(wc + nf * 16 + arow) * 32 + ak];
      bf2[nf] = *(const short8*)&Ws[cur][1][(wc + nf * 16 + arow) * 32 + ak];
    }
    #pragma unroll
    for (int mf = 0; mf < 4; mf++)
      #pragma unroll
      for (int nf = 0; nf < 4; nf++) {
        acc1[mf][nf] = __builtin_amdgcn_mfma_f32_16x16x32_bf16(a[mf], bf1[nf], acc1[mf][nf], 0, 0, 0);
        acc2[mf][nf] = __builtin_amdgcn_mfma_f32_16x16x32_bf16(a[mf], bf2[nf], acc2[mf][nf], 0, 0, 0);
      }
    cur ^= 1;
  }

  // epilogue: C/D layout col=lane&15, row=(lane>>4)*4+r  [m89-verified]
  int crow = (lane >> 4) * 4, ccol = lane & 15;
  #pragma unroll
  for (int mf = 0; mf < 4; mf++) {
    #pragma unroll
    for (int nf = 0; nf < 4; nf++) {
      int col = n0 + wc + nf * 16 + ccol;
      float bb1 = b1[col], bb2 = b2[col];
      #pragma unroll
      for (int r = 0; r < 4; r++) {
        int row = m0 + wr + mf * 16 + crow + r;
        float z1 = acc1[mf][nf][r] + bb1;
        float z2 = acc2[mf][nf][r] + bb2;
        float th = 1.f - 2.f / (__expf(2.f * z1) + 1.f);
        float sg = 1.f / (1.f + __expf(-z2));
        out[(size_t)row * D_ + col] = th * sg;
      }
    }
  }
}

// ------------- f_hat[n,t,d] = sum_l att[n,t,l]*f1[n,l,d]; out0 += ------------
// 8-deep explicit prefetch breaks the dependent-load chain (was 1 load in
// flight -> ~900cy exposed per l; now ~8 in flight).
__global__ __launch_bounds__(64)
void fhat_add(const float* __restrict__ f1, const float* __restrict__ att,
              float* __restrict__ out0) {
  int n = blockIdx.x >> 3, dq = blockIdx.x & 7;
  int d = dq * 64 + threadIdx.x;
  const float* f1n = f1 + (size_t)n * L_ * D_ + d;
  const float* an = att + (size_t)n * T_ * L_;
  float acc[32];
  #pragma unroll
  for (int i = 0; i < 32; i++) acc[i] = 0.f;
  float curv[8], nxt[8];
  #pragma unroll
  for (int j = 0; j < 8; j++) curv[j] = f1n[(size_t)j * D_];
  #pragma unroll 1
  for (int c = 0; c < 24; ++c) {        // 24*8 = 192 l's; tail 4 below
    int lb = c * 8;
    if (c < 23) {
      #pragma unroll
      for (int j = 0; j < 8; j++) nxt[j] = f1n[(size_t)(lb + 8 + j) * D_];
    }
    #pragma unroll
    for (int j = 0; j < 8; j++) {
      float f = curv[j];
      #pragma unroll
      for (int tt = 0; tt < 32; tt++)
        acc[tt] = fmaf(an[tt * L_ + lb + j], f, acc[tt]);
    }
    #pragma unroll
    for (int j = 0; j < 8; j++) curv[j] = nxt[j];
  }
  #pragma unroll
  for (int l = 192; l < 196; l++) {
    float f = f1n[(size_t)l * D_];
    #pragma unroll
    for (int tt = 0; tt < 32; tt++)
      acc[tt] = fmaf(an[tt * L_ + l], f, acc[tt]);
  }
  float* o = out0 + (size_t)n * T_ * D_ + d;
  #pragma unroll
  for (int tt = 0; tt < 32; tt++) o[(size_t)tt * D_] += acc[tt];
}

extern "C" void kernel_launch(void* const* d_in, const int* in_sizes, int n_in,
                              void* d_out, int out_size, void* d_ws, size_t ws_size,
                              hipStream_t stream) {
  const float* f1    = (const float*)d_in[0];
  const float* f2    = (const float*)d_in[1];
  const float* w_att = (const float*)d_in[2];
  const float* b_att = (const float*)d_in[3];
  const float* n1w1  = (const float*)d_in[4];
  const float* n1b1  = (const float*)d_in[5];
  const float* n1w2  = (const float*)d_in[6];
  const float* n1b2  = (const float*)d_in[7];
  const float* n2w1  = (const float*)d_in[8];
  const float* n2b1  = (const float*)d_in[9];
  const float* n2w2  = (const float*)d_in[10];
  const float* n2b2  = (const float*)d_in[11];

  float* out0 = (float*)d_out;                        // [64][32][512]
  float* out1 = out0 + (size_t)N_ * T_ * D_;          // [64][196][512]
  float* att  = out1 + (size_t)N_ * L_ * D_;          // [64][32][196]

  char* ws = (char*)d_ws;
  auto alloc = [&](size_t bytes) { char* p = ws; ws += (bytes + 255) & ~(size_t)255; return p; };
  unsigned short* f1b   = (unsigned short*)alloc((size_t)ROWS1_ * D_ * 2);
  unsigned short* f2b   = (unsigned short*)alloc((size_t)ROWS2_ * D_ * 2);
  unsigned short* w1t_1 = (unsigned short*)alloc((size_t)D_ * D_ * 2);
  unsigned short* w2t_1 = (unsigned short*)alloc((size_t)D_ * D_ * 2);
  unsigned short* w1t_2 = (unsigned short*)alloc((size_t)D_ * D_ * 2);
  unsigned short* w2t_2 = (unsigned short*)alloc((size_t)D_ * D_ * 2);
  float* s1 = (float*)alloc((size_t)ROWS1_ * 4);
  float* s2 = (float*)alloc((size_t)ROWS2_ * 4);

  cvt_dots<<<(ROWS1_ + ROWS2_) / 4, 256, 0, stream>>>(f1, f2, w_att, f1b, f2b, s1, s2);
  wt_cvt<<<dim3(64, 4), 256, 0, stream>>>(n1w1, n1w2, n2w1, n2w2, w1t_1, w2t_1, w1t_2, w2t_2);
  softmax_att<<<N_ * T_, 64, 0, stream>>>(s1, s2, b_att, att);
  glu_gemm<<<NWG1_ + NWG2_, 256, 0, stream>>>(f1b, f2b, w1t_1, w2t_1, w1t_2, w2t_2,
                                              n1b1, n1b2, n2b1, n2b2, out1, out0);
  fhat_add<<<N_ * 8, 64, 0, stream>>>(f1, att, out0);
}

// Round 5
// 152.458 us; speedup vs baseline: 1.5376x; 1.5376x over previous
//
#include <hip/hip_runtime.h>
#include <hip/hip_bf16.h>
#include <cstdint>
#include <cstddef>

#define N_  64
#define L_  196
#define T_  32
#define D_  512
#define LP_ 256                   // l padded to 256 (zero-fill) for MFMA K
#define ROWS1_ (N_ * L_)          // 12544
#define ROWS2_ (N_ * T_)          // 2048
#define MT1_   (ROWS1_ / 128)     // 98
#define NWG1_  (MT1_ * 4)         // 392
#define NWG2_  ((ROWS2_ / 128) * 4) // 64

typedef __attribute__((ext_vector_type(8))) short short8;
typedef __attribute__((ext_vector_type(4))) float f32x4;

// f32 -> bf16 bits, round-to-nearest-even
__device__ inline unsigned short f2bf(float f) {
  unsigned u = __builtin_bit_cast(unsigned, f);
  u = u + 0x7FFFu + ((u >> 16) & 1u);
  return (unsigned short)(u >> 16);
}

// ---- fused: bf16 convert of f1/f2 rows + attention dot s = row @ w_att ------
__global__ __launch_bounds__(256)
void cvt_dots(const float* __restrict__ f1, const float* __restrict__ f2,
              const float* __restrict__ w,
              unsigned short* __restrict__ f1b, unsigned short* __restrict__ f2b,
              float* __restrict__ s1, float* __restrict__ s2) {
  int row = blockIdx.x * 4 + (threadIdx.x >> 6);
  int lane = threadIdx.x & 63;
  bool isf1 = row < ROWS1_;
  const float* src = isf1 ? (f1 + (size_t)row * D_) : (f2 + (size_t)(row - ROWS1_) * D_);
  unsigned short* dst = isf1 ? (f1b + (size_t)row * D_) : (f2b + (size_t)(row - ROWS1_) * D_);
  float4 x0 = ((const float4*)src)[lane];
  float4 x1 = ((const float4*)src)[lane + 64];
  float4 w0 = ((const float4*)w)[lane];
  float4 w1 = ((const float4*)w)[lane + 64];
  float d = x0.x * w0.x + x0.y * w0.y + x0.z * w0.z + x0.w * w0.w
          + x1.x * w1.x + x1.y * w1.y + x1.z * w1.z + x1.w * w1.w;
  ushort4 o0, o1;
  o0.x = f2bf(x0.x); o0.y = f2bf(x0.y); o0.z = f2bf(x0.z); o0.w = f2bf(x0.w);
  o1.x = f2bf(x1.x); o1.y = f2bf(x1.y); o1.z = f2bf(x1.z); o1.w = f2bf(x1.w);
  ((ushort4*)dst)[lane] = o0;
  ((ushort4*)dst)[lane + 64] = o1;
  #pragma unroll
  for (int s = 32; s; s >>= 1) d += __shfl_xor(d, s);
  if (lane == 0) {
    if (isf1) s1[row] = d; else s2[row - ROWS1_] = d;
  }
}

// ------------- weight transpose + convert: Wt[n][k] = bf16(W[k][n]) -----------
__global__ __launch_bounds__(256)
void wt_cvt(const float* __restrict__ w0, const float* __restrict__ w1,
            const float* __restrict__ w2, const float* __restrict__ w3,
            unsigned short* __restrict__ o0, unsigned short* __restrict__ o1,
            unsigned short* __restrict__ o2, unsigned short* __restrict__ o3) {
  const float* W = (blockIdx.y == 0) ? w0 : (blockIdx.y == 1) ? w1 : (blockIdx.y == 2) ? w2 : w3;
  unsigned short* O = (blockIdx.y == 0) ? o0 : (blockIdx.y == 1) ? o1 : (blockIdx.y == 2) ? o2 : o3;
  int k0 = (blockIdx.x >> 3) * 64, n0 = (blockIdx.x & 7) * 64;
  __shared__ float tl[64][65];
  int t = threadIdx.x;
  #pragma unroll
  for (int i = 0; i < 16; i++) {
    int e = t + i * 256;
    int r = e >> 6, c = e & 63;
    tl[r][c] = W[(size_t)(k0 + r) * D_ + n0 + c];
  }
  __syncthreads();
  #pragma unroll
  for (int i = 0; i < 16; i++) {
    int e = t + i * 256;
    int r = e >> 6, c = e & 63;
    O[(size_t)(n0 + r) * D_ + k0 + c] = f2bf(tl[c][r]);
  }
}

// -------- f1 transpose+cvt: f1t[n][d][l] = bf16(f1[n][l][d]), l padded 256 ---
// grid: n(64) x lchunk(4) x dchunk(8) = 2048 blocks
__global__ __launch_bounds__(256)
void f1t_cvt(const float* __restrict__ f1, unsigned short* __restrict__ f1t) {
  int bi = blockIdx.x;
  int n = bi >> 5, rem = bi & 31;
  int l0 = (rem >> 3) * 64, d0 = (rem & 7) * 64;
  __shared__ float tl[64][65];
  int t = threadIdx.x;
  #pragma unroll
  for (int i = 0; i < 16; i++) {
    int e = t + i * 256;
    int r = e >> 6, c = e & 63;
    int l = l0 + r;
    tl[r][c] = (l < L_) ? f1[((size_t)n * L_ + l) * D_ + d0 + c] : 0.f;
  }
  __syncthreads();
  #pragma unroll
  for (int i = 0; i < 16; i++) {
    int e = t + i * 256;
    int r = e >> 6, c = e & 63;     // r = d-within-tile, c = l-within-tile
    f1t[((size_t)n * D_ + d0 + r) * LP_ + l0 + c] = f2bf(tl[c][r]);
  }
}

// ------ softmax over L per (n,t): writes f32 att (output) + bf16 att_b -------
__global__ __launch_bounds__(64)
void softmax_att(const float* __restrict__ s1, const float* __restrict__ s2,
                 const float* __restrict__ b_att, float* __restrict__ att,
                 unsigned short* __restrict__ attb) {
  int b = blockIdx.x;           // n*32 + t
  int n = b >> 5;
  int lane = threadIdx.x;
  float s2v = s2[b] + b_att[0];
  const float* s1n = s1 + (size_t)n * L_;
  float v[4];
  float mx = -1e30f;
  #pragma unroll
  for (int j = 0; j < 4; j++) {
    int l = lane + j * 64;
    v[j] = (l < L_) ? (s1n[l] + s2v) : -1e30f;
    mx = fmaxf(mx, v[j]);
  }
  #pragma unroll
  for (int s = 32; s; s >>= 1) mx = fmaxf(mx, __shfl_xor(mx, s));
  float sum = 0.f;
  #pragma unroll
  for (int j = 0; j < 4; j++) { v[j] = __expf(v[j] - mx); sum += v[j]; }
  #pragma unroll
  for (int s = 32; s; s >>= 1) sum += __shfl_xor(sum, s);
  float inv = 1.f / sum;
  float* an = att + (size_t)b * L_;
  unsigned short* ab = attb + (size_t)b * LP_;
  #pragma unroll
  for (int j = 0; j < 4; j++) {
    int l = lane + j * 64;
    float p = v[j] * inv;
    if (l < L_) an[l] = p;
    ab[l] = (l < L_) ? f2bf(p) : (unsigned short)0;   // zero K-pad
  }
}

// -------- fused GLU GEMM (both problems in one grid) -------------------------
__global__ __launch_bounds__(256, 2)
void glu_gemm(const unsigned short* __restrict__ Xb1, const unsigned short* __restrict__ Xb2,
              const unsigned short* __restrict__ W1t_1, const unsigned short* __restrict__ W2t_1,
              const unsigned short* __restrict__ W1t_2, const unsigned short* __restrict__ W2t_2,
              const float* __restrict__ b1_1, const float* __restrict__ b2_1,
              const float* __restrict__ b1_2, const float* __restrict__ b2_2,
              float* __restrict__ o1, float* __restrict__ o0) {
  int nwg = gridDim.x;
  int q = nwg >> 3;                         // nwg % 8 == 0 by construction
  int orig = blockIdx.x;
  int bid = (orig & 7) * q + (orig >> 3);   // XCD-chunked swizzle (bijective)
  const unsigned short *Xb, *W1t, *W2t;
  const float *b1, *b2;
  float* out;
  if (bid < NWG1_) { Xb = Xb1; W1t = W1t_1; W2t = W2t_1; b1 = b1_1; b2 = b2_1; out = o1; }
  else { bid -= NWG1_; Xb = Xb2; W1t = W1t_2; W2t = W2t_2; b1 = b1_2; b2 = b2_2; out = o0; }
  int nt = bid & 3, mt = bid >> 2;
  int m0 = mt * 128, n0 = nt * 128;
  int t = threadIdx.x, lane = t & 63, wave = t >> 6;
  int wr = (wave >> 1) * 64, wc = (wave & 1) * 64;

  __shared__ alignas(16) unsigned short Xs[2][4096];      // [128][32]
  __shared__ alignas(16) unsigned short Ws[2][2][4096];   // [mat][128][32]

  auto stage = [&](int buf, int k0) {
    #pragma unroll
    for (int i = 0; i < 2; i++) {
      int c = t + i * 256;
      const unsigned short* g = Xb + (size_t)(m0 + (c >> 2)) * D_ + k0 + (c & 3) * 8;
      unsigned short* l = &Xs[buf][(size_t)(wave * 64 + i * 256) * 8];
      __builtin_amdgcn_global_load_lds((const __attribute__((address_space(1))) unsigned int*)g,
                                       (__attribute__((address_space(3))) unsigned int*)l,
                                       16, 0, 0);
    }
    #pragma unroll
    for (int w = 0; w < 2; w++) {
      const unsigned short* Wt = w ? W2t : W1t;
      #pragma unroll
      for (int i = 0; i < 2; i++) {
        int c = t + i * 256;
        const unsigned short* g = Wt + (size_t)(n0 + (c >> 2)) * D_ + k0 + (c & 3) * 8;
        unsigned short* l = &Ws[buf][w][(size_t)(wave * 64 + i * 256) * 8];
        __builtin_amdgcn_global_load_lds((const __attribute__((address_space(1))) unsigned int*)g,
                                         (__attribute__((address_space(3))) unsigned int*)l,
                                         16, 0, 0);
      }
    }
  };

  f32x4 acc1[4][4], acc2[4][4];
  #pragma unroll
  for (int i = 0; i < 4; i++)
    #pragma unroll
    for (int j = 0; j < 4; j++) { acc1[i][j] = (f32x4)(0.f); acc2[i][j] = (f32x4)(0.f); }

  stage(0, 0);
  int cur = 0;
  int arow = lane & 15, ak = (lane >> 4) * 8;
  for (int ks = 0; ks < 16; ++ks) {
    __syncthreads();
    if (ks < 15) stage(cur ^ 1, (ks + 1) * 32);
    short8 a[4], bf1[4], bf2[4];
    #pragma unroll
    for (int mf = 0; mf < 4; mf++)
      a[mf] = *(const short8*)&Xs[cur][(wr + mf * 16 + arow) * 32 + ak];
    #pragma unroll
    for (int nf = 0; nf < 4; nf++) {
      bf1[nf] = *(const short8*)&Ws[cur][0][(wc + nf * 16 + arow) * 32 + ak];
      bf2[nf] = *(const short8*)&Ws[cur][1][(wc + nf * 16 + arow) * 32 + ak];
    }
    #pragma unroll
    for (int mf = 0; mf < 4; mf++)
      #pragma unroll
      for (int nf = 0; nf < 4; nf++) {
        acc1[mf][nf] = __builtin_amdgcn_mfma_f32_16x16x32_bf16(a[mf], bf1[nf], acc1[mf][nf], 0, 0, 0);
        acc2[mf][nf] = __builtin_amdgcn_mfma_f32_16x16x32_bf16(a[mf], bf2[nf], acc2[mf][nf], 0, 0, 0);
      }
    cur ^= 1;
  }

  int crow = (lane >> 4) * 4, ccol = lane & 15;
  #pragma unroll
  for (int mf = 0; mf < 4; mf++) {
    #pragma unroll
    for (int nf = 0; nf < 4; nf++) {
      int col = n0 + wc + nf * 16 + ccol;
      float bb1 = b1[col], bb2 = b2[col];
      #pragma unroll
      for (int r = 0; r < 4; r++) {
        int row = m0 + wr + mf * 16 + crow + r;
        float z1 = acc1[mf][nf][r] + bb1;
        float z2 = acc2[mf][nf][r] + bb2;
        float th = 1.f - 2.f / (__expf(2.f * z1) + 1.f);
        float sg = 1.f / (1.f + __expf(-z2));
        out[(size_t)row * D_ + col] = th * sg;
      }
    }
  }
}

// -------- f_hat via MFMA: out0[n] += att_b[n] (32x256) @ f1t[n]^T (256x512) --
// grid = 64n x 4dq = 256 blocks, 4 waves; wave w owns d-cols [dq*128+w*32, +32)
// A/B fragments loaded directly from global (L2-resident), no LDS.
__global__ __launch_bounds__(256)
void fhat_mfma(const unsigned short* __restrict__ attb,   // [64][32][256]
               const unsigned short* __restrict__ f1t,    // [64][512][256]
               float* __restrict__ out0) {                // [64][32][512]
  int n = blockIdx.x >> 2, dq = blockIdx.x & 3;
  int lane = threadIdx.x & 63, wave = threadIdx.x >> 6;
  int d0 = dq * 128 + wave * 32;
  int arow = lane & 15, ak = (lane >> 4) * 8;
  const unsigned short* A = attb + (size_t)n * T_ * LP_;
  const unsigned short* B = f1t + ((size_t)n * D_ + d0) * LP_;
  f32x4 acc[2][2];
  #pragma unroll
  for (int i = 0; i < 2; i++)
    #pragma unroll
    for (int j = 0; j < 2; j++) acc[i][j] = (f32x4)(0.f);
  #pragma unroll 2
  for (int kk = 0; kk < 8; kk++) {
    int k0 = kk * 32;
    short8 a[2], b[2];
    #pragma unroll
    for (int mt = 0; mt < 2; mt++)
      a[mt] = *(const short8*)&A[(size_t)(mt * 16 + arow) * LP_ + k0 + ak];
    #pragma unroll
    for (int nt2 = 0; nt2 < 2; nt2++)
      b[nt2] = *(const short8*)&B[(size_t)(nt2 * 16 + arow) * LP_ + k0 + ak];
    #pragma unroll
    for (int mt = 0; mt < 2; mt++)
      #pragma unroll
      for (int nt2 = 0; nt2 < 2; nt2++)
        acc[mt][nt2] = __builtin_amdgcn_mfma_f32_16x16x32_bf16(a[mt], b[nt2], acc[mt][nt2], 0, 0, 0);
  }
  int crow = (lane >> 4) * 4, ccol = lane & 15;
  #pragma unroll
  for (int mt = 0; mt < 2; mt++) {
    #pragma unroll
    for (int nt2 = 0; nt2 < 2; nt2++) {
      int d = d0 + nt2 * 16 + ccol;
      #pragma unroll
      for (int r = 0; r < 4; r++) {
        int tt = mt * 16 + crow + r;
        size_t idx = ((size_t)n * T_ + tt) * D_ + d;
        out0[idx] += acc[mt][nt2][r];
      }
    }
  }
}

extern "C" void kernel_launch(void* const* d_in, const int* in_sizes, int n_in,
                              void* d_out, int out_size, void* d_ws, size_t ws_size,
                              hipStream_t stream) {
  const float* f1    = (const float*)d_in[0];
  const float* f2    = (const float*)d_in[1];
  const float* w_att = (const float*)d_in[2];
  const float* b_att = (const float*)d_in[3];
  const float* n1w1  = (const float*)d_in[4];
  const float* n1b1  = (const float*)d_in[5];
  const float* n1w2  = (const float*)d_in[6];
  const float* n1b2  = (const float*)d_in[7];
  const float* n2w1  = (const float*)d_in[8];
  const float* n2b1  = (const float*)d_in[9];
  const float* n2w2  = (const float*)d_in[10];
  const float* n2b2  = (const float*)d_in[11];

  float* out0 = (float*)d_out;                        // [64][32][512]
  float* out1 = out0 + (size_t)N_ * T_ * D_;          // [64][196][512]
  float* att  = out1 + (size_t)N_ * L_ * D_;          // [64][32][196]

  char* ws = (char*)d_ws;
  auto alloc = [&](size_t bytes) { char* p = ws; ws += (bytes + 255) & ~(size_t)255; return p; };
  unsigned short* f1b   = (unsigned short*)alloc((size_t)ROWS1_ * D_ * 2);
  unsigned short* f2b   = (unsigned short*)alloc((size_t)ROWS2_ * D_ * 2);
  unsigned short* w1t_1 = (unsigned short*)alloc((size_t)D_ * D_ * 2);
  unsigned short* w2t_1 = (unsigned short*)alloc((size_t)D_ * D_ * 2);
  unsigned short* w1t_2 = (unsigned short*)alloc((size_t)D_ * D_ * 2);
  unsigned short* w2t_2 = (unsigned short*)alloc((size_t)D_ * D_ * 2);
  unsigned short* f1t   = (unsigned short*)alloc((size_t)N_ * D_ * LP_ * 2);  // 16.8 MB
  unsigned short* attb  = (unsigned short*)alloc((size_t)N_ * T_ * LP_ * 2);  // 1.05 MB
  float* s1 = (float*)alloc((size_t)ROWS1_ * 4);
  float* s2 = (float*)alloc((size_t)ROWS2_ * 4);

  cvt_dots<<<(ROWS1_ + ROWS2_) / 4, 256, 0, stream>>>(f1, f2, w_att, f1b, f2b, s1, s2);
  wt_cvt<<<dim3(64, 4), 256, 0, stream>>>(n1w1, n1w2, n2w1, n2w2, w1t_1, w2t_1, w1t_2, w2t_2);
  glu_gemm<<<NWG1_ + NWG2_, 256, 0, stream>>>(f1b, f2b, w1t_1, w2t_1, w1t_2, w2t_2,
                                              n1b1, n1b2, n2b1, n2b2, out1, out0);
  f1t_cvt<<<N_ * 32, 256, 0, stream>>>(f1, f1t);
  softmax_att<<<N_ * T_, 64, 0, stream>>>(s1, s2, b_att, att, attb);
  fhat_mfma<<<N_ * 4, 256, 0, stream>>>(attb, f1t, out0);
}